// Round 16
// baseline (320.373 us; speedup 1.0000x reference)
//
#include <hip/hip_runtime.h>
#include <math.h>

#define NPOS 8192
#define MAXIT 50
#define TOLF 2e-3f           // early-stop bonus; may never fire (r14 evidence)
#define NM   41              // Fourier modes m = 0..40 (mode 41: ~1e-9 relative)
#define NR   82              // basis rows: 41 cos + 41 sin
#define NSLOT 656            // NR * 8 batches
#define NBLK 64              // i-chunk blocks
#define CHUNK 128            // i per block

// ws float offsets
#define OFF_LA    0          // 65536 log(alpha)
#define OFF_F     65536      // 65536 potential f
#define OFF_CB    131072     // 8 stabilizer cb = max(la)
#define OFF_G     131080     // 41 spectral coeffs g_m
#define OFF_SLOT  131136     // 800 uints gap slots
#define OFF_BASIS 132096     // NBLK*NR*CHUNK = 671744 floats (2.7 MB)
#define OFF_PART  803840     // 2*NSLOT*NBLK = 83968 floats (double-buffered on k&1)

#define SLOT_DMAX 0          // 50*8
#define SLOT_DMIN 400        // 50*8

__device__ inline unsigned fkey(float x) {
  unsigned b = __float_as_uint(x);
  return (b & 0x80000000u) ? ~b : (b | 0x80000000u);
}
__device__ inline float fval(unsigned k) {
  unsigned b = (k & 0x80000000u) ? (k ^ 0x80000000u) : ~k;
  return __uint_as_float(b);
}

// run body k iff gap_{k-1} >= TOLF (never-run slots -> -inf -> stay stopped)
__device__ inline bool run_iter(const unsigned* slots, int k) {
  if (k == 0) return true;
  const unsigned* dmax = slots + SLOT_DMAX + (k - 1) * 8;
  const unsigned* dmin = slots + SLOT_DMIN + (k - 1) * 8;
  float s = 0.f;
#pragma unroll
  for (int b = 0; b < 8; ++b) s += fval(dmax[b]) - fval(dmin[b]);
  return (s * 0.125f) >= TOLF;
}

__global__ __launch_bounds__(256) void setup_base(const float* __restrict__ alpha,
                                                  float* __restrict__ ws) {
  int id = blockIdx.x * 256 + threadIdx.x;        // grid 256 -> 65536
  float a = alpha[id];
  ws[OFF_LA + id] = (a > 0.f) ? logf(a) : -INFINITY;
  ws[OFF_F + id] = 0.f;
  unsigned* slots = (unsigned*)(ws + OFF_SLOT);
  if (id < 400) {
    slots[SLOT_DMAX + id] = fkey(-INFINITY);
    slots[SLOT_DMIN + id] = fkey(INFINITY);
  }
}

__global__ __launch_bounds__(256) void setup_cb(float* __restrict__ ws) {
  int b = blockIdx.x;
  const float* lap = ws + OFF_LA + b * NPOS;
  float m = -INFINITY;
  for (int i = threadIdx.x; i < NPOS; i += 256) m = fmaxf(m, lap[i]);
#pragma unroll
  for (int o = 1; o < 64; o <<= 1) m = fmaxf(m, __shfl_xor(m, o, 64));
  __shared__ float r[4];
  if ((threadIdx.x & 63) == 0) r[threadIdx.x >> 6] = m;
  __syncthreads();
  if (threadIdx.x == 0)
    ws[OFF_CB + b] = fmaxf(fmaxf(r[0], r[1]), fmaxf(r[2], r[3]));
}

// g_m = (m==0?1:2)/16384 * sum_{d=-8191..8191} w(|d|) cos(theta_m d)
// (exact periodized DFT of the actual kernel row; missing d=-8192 term ~ e^-200 = 0)
__global__ __launch_bounds__(256) void setup_am(const float* __restrict__ kern,
                                                float* __restrict__ ws) {
  const int m = blockIdx.x;                       // grid 41
  float s = 0.f;
  for (int d = threadIdx.x; d < NPOS; d += 256) {
    float w = expf(kern[d]);                      // kernel row 0; Toeplitz-exact
    float coef = (d == 0) ? 1.f : 2.f;
    float ang = 6.28318530718f * (float)((m * d) & 16383) * (1.f / 16384.f);
    s += coef * w * cosf(ang);
  }
#pragma unroll
  for (int o = 1; o < 64; o <<= 1) s += __shfl_xor(s, o, 64);
  __shared__ float r[4];
  if ((threadIdx.x & 63) == 0) r[threadIdx.x >> 6] = s;
  __syncthreads();
  if (threadIdx.x == 0) {
    float W = (r[0] + r[1]) + (r[2] + r[3]);
    ws[OFF_G + m] = W * ((m == 0) ? 1.f : 2.f) * (1.f / 16384.f);
  }
}

// basis[blk][r][ii]: r<41 -> cos(th_r j), r>=41 -> sin(th_{r-41} j), j = blk*128+ii
__global__ __launch_bounds__(256) void setup_basis(float* __restrict__ ws) {
  int id = blockIdx.x * 256 + threadIdx.x;        // grid 2624 -> 671744
  int ii = id & 127;
  int e  = id >> 7;
  int blk = e / NR;
  int r   = e - blk * NR;
  int m = (r < NM) ? r : r - NM;
  int j = (blk << 7) + ii;
  float ang = 6.28318530718f * (float)((m * j) & 16383) * (1.f / 16384.f);
  ws[OFF_BASIS + (size_t)blk * (NR * CHUNK) + r * CHUNK + ii] =
      (r < NM) ? cosf(ang) : sinf(ang);
}

// project eu0 = exp(la - cb) -> part[0]
__global__ __launch_bounds__(1024) void setup_proj(float* __restrict__ ws) {
  const int blk = blockIdx.x;                     // grid 64
  const int t = threadIdx.x, ii = t & 127, b = t >> 7;
  const int i = (blk << 7) + ii;
  __shared__ float eul[8][129];
  eul[b][ii] = expf(ws[OFF_LA + b * NPOS + i] - ws[OFF_CB + b]);
  __syncthreads();
  const float* bas = ws + OFF_BASIS + (size_t)blk * (NR * CHUNK);
  float* part = ws + OFF_PART;
  if (t < NSLOT) {
    int r = t >> 3, bb = t & 7;
    const float* brow = bas + (r << 7);
    float s = 0.f;
#pragma unroll
    for (int q = 0; q < CHUNK; ++q) s += brow[q] * eul[bb][q];
    part[((size_t)t << 6) + blk] = s;
  }
}

// ---- one fused spectral iteration (grid 64 x 1024 thr) ----
// phase0: reduce part[k&1] (64 fixed-order partials/slot) -> CS in LDS
// phase1: v[b,i] = sum_m g_m (cos*C + sin*S); epilogue: g,f,d,eu',gap slots
// phase2: project eu' chunk onto basis -> part[(k+1)&1][slot][blk]
__global__ __launch_bounds__(1024) void iter_k(
    const float* __restrict__ la, float* __restrict__ f,
    const float* __restrict__ cb, const float* __restrict__ gw,
    unsigned* __restrict__ slots, const float* __restrict__ basis,
    float* __restrict__ part, int k)
{
  if (!run_iter(slots, k)) return;
  const int blk = blockIdx.x;
  const int t = threadIdx.x, ii = t & 127, b = t >> 7;
  const int i = (blk << 7) + ii;

  __shared__ float CS[NSLOT];
  __shared__ float gl[NM];
  __shared__ float eul[8][129];

  // phase 0: reduce previous partials (fixed order -> deterministic, identical
  // across blocks)
  if (t < NSLOT) {
    const float4* p = (const float4*)(part + (((size_t)(k & 1) * NSLOT + t) << 6));
    float s = 0.f;
#pragma unroll
    for (int q = 0; q < 16; ++q) {
      float4 v4 = p[q];
      s += (v4.x + v4.y) + (v4.z + v4.w);
    }
    CS[t] = s;
  }
  if (t >= 1024 - NM) gl[t - (1024 - NM)] = gw[t - (1024 - NM)];
  __syncthreads();

  // phase 1: reconstruction + fused epilogue
  const float* bas = basis + (size_t)blk * (NR * CHUNK);
  float v = 0.f;
#pragma unroll 8
  for (int m = 0; m < NM; ++m) {
    float c = bas[(m << 7) + ii];
    float s = bas[((NM + m) << 7) + ii];
    v += gl[m] * (c * CS[(m << 3) + b] + s * CS[((NM + m) << 3) + b]);
  }
  const float cbb = cb[b];
  float g2 = -2.f * (logf(v) + cbb);
  float* fp = f + (size_t)b * NPOS + i;
  float fo = *fp;
  float d  = fo - g2;
  float fn = 0.5f * (fo + g2);
  *fp = fn;
  float un = 0.5f * fn + la[(size_t)b * NPOS + i];
  eul[b][ii] = expf(un - cbb);

  float dmax = d, dmin = d;
#pragma unroll
  for (int o = 1; o < 64; o <<= 1) {   // wave-wide; each wave has a single b
    dmax = fmaxf(dmax, __shfl_xor(dmax, o, 64));
    dmin = fminf(dmin, __shfl_xor(dmin, o, 64));
  }
  if ((t & 63) == 0) {                 // 2 waves per b; max/min tolerate dupes
    atomicMax(&slots[SLOT_DMAX + k * 8 + b], fkey(dmax));
    atomicMin(&slots[SLOT_DMIN + k * 8 + b], fkey(dmin));
  }
  __syncthreads();

  // phase 2: project eu' chunk -> part[(k+1)&1]
  if (t < NSLOT) {
    int r = t >> 3, bb = t & 7;
    const float* brow = bas + (r << 7);
    float s = 0.f;
#pragma unroll
    for (int q = 0; q < CHUNK; ++q) s += brow[q] * eul[bb][q];
    part[(((size_t)((k + 1) & 1) * NSLOT + t) << 6) + blk] = s;
  }
}

__global__ __launch_bounds__(256) void value_k(const float* __restrict__ alpha,
                                               const float* __restrict__ ws,
                                               float* __restrict__ out) {
  int b = blockIdx.x;
  const float* fp = ws + OFF_F + b * NPOS;
  const float* ap = alpha + b * NPOS;
  float s = 0.f;
  for (int i = threadIdx.x; i < NPOS; i += 256) s = fmaf(fp[i], ap[i], s);
#pragma unroll
  for (int o = 1; o < 64; o <<= 1) s += __shfl_xor(s, o, 64);
  __shared__ float red[4];
  if ((threadIdx.x & 63) == 0) red[threadIdx.x >> 6] = s;
  __syncthreads();
  if (threadIdx.x == 0) out[b] = -(red[0] + red[1] + red[2] + red[3]);
}

extern "C" void kernel_launch(void* const* d_in, const int* in_sizes, int n_in,
                              void* d_out, int out_size, void* d_ws, size_t ws_size,
                              hipStream_t stream) {
  const float* alpha = (const float*)d_in[0];
  const float* kern  = (const float*)d_in[1];
  float* ws  = (float*)d_ws;
  float* out = (float*)d_out;

  float* lap = ws + OFF_LA;
  float* fp  = ws + OFF_F;
  float* cbp = ws + OFF_CB;
  float* gwp = ws + OFF_G;
  unsigned* slots = (unsigned*)(ws + OFF_SLOT);
  float* basisp = ws + OFF_BASIS;
  float* partp  = ws + OFF_PART;

  setup_base<<<256, 256, 0, stream>>>(alpha, ws);
  setup_cb<<<8, 256, 0, stream>>>(ws);
  setup_am<<<41, 256, 0, stream>>>(kern, ws);
  setup_basis<<<2624, 256, 0, stream>>>(ws);
  setup_proj<<<NBLK, 1024, 0, stream>>>(ws);
  for (int k = 0; k < MAXIT; ++k)
    iter_k<<<NBLK, 1024, 0, stream>>>(lap, fp, cbp, gwp, slots, basisp, partp, k);
  value_k<<<8, 256, 0, stream>>>(alpha, ws, out);
}